// Round 10
// baseline (5852.673 us; speedup 1.0000x reference)
//
#include <hip/hip_runtime.h>
#include <cstdint>
#include <cstddef>

#define DI __device__ __forceinline__

typedef __bf16 bf16x8 __attribute__((ext_vector_type(8)));
typedef float  f32x4  __attribute__((ext_vector_type(4)));
typedef unsigned short ushort_t;

constexpr int BATCH = 1024;
constexpr int HID   = 2048;
constexpr int IN    = 76;
constexpr int SENC  = 49;
constexpr int TDEC  = 25;
constexpr int KX    = 128;          // x padded to 128 cols
constexpr int KP    = KX + HID;     // 2176 packed K
constexpr int BK    = 64;           // K-step (one LDS tile)
constexpr int KTT   = KP / BK;      // 34 K-steps (even -> clean unroll-by-2)
constexpr int OSTR  = TDEC * IN;    // 1900 (row stride of decoder_inputs and d_out)

DI unsigned short f2bf(float f) {
  union { float f; unsigned u; } v; v.f = f;
  unsigned u = v.u;
  return (unsigned short)((u + 0x7fffu + ((u >> 16) & 1u)) >> 16);  // RTNE
}

DI float bf2f(unsigned short h) {
  union { unsigned u; float f; } v; v.u = ((unsigned)h) << 16;
  return v.f;
}

DI f32x4 mfma16(bf16x8 a, bf16x8 b, f32x4 c) {
  return __builtin_amdgcn_mfma_f32_16x16x32_bf16(a, b, c, 0, 0, 0);
}

DI void gload_lds16(const void* g, void* l) {
  __builtin_amdgcn_global_load_lds((const __attribute__((address_space(1))) void*)g,
                                   (__attribute__((address_space(3))) void*)l,
                                   16, 0, 0);
}

DI float sigmoidf_(float x) { return 1.0f / (1.0f + __expf(-x)); }
DI float tanhf_(float x)    { return 1.0f - 2.0f / (1.0f + __expf(2.0f * x)); }

// ---------------- packing kernels (run once per launch) ----------------

__global__ void pack_W(const float* __restrict__ Wih, const float* __restrict__ Whh,
                       ushort_t* __restrict__ Wp) {
  int idx = blockIdx.x * 256 + threadIdx.x;
  if (idx >= 6144 * KP) return;
  int n = idx / KP;
  int k = idx - n * KP;
  float v = 0.f;
  if (k < IN)        v = Wih[(size_t)n * IN + k];
  else if (k >= KX)  v = Whh[(size_t)n * HID + (k - KX)];
  Wp[idx] = f2bf(v);
}

__global__ void pack_xe(const float* __restrict__ enc, ushort_t* __restrict__ xe) {
  int idx = blockIdx.x * 256 + threadIdx.x;
  if (idx >= SENC * BATCH * KX) return;
  int t = idx >> 17;
  int rem = idx & 131071;
  int b = rem >> 7, k = rem & 127;
  float v = (k < IN) ? enc[(size_t)b * (SENC * IN) + t * IN + k] : 0.f;
  xe[idx] = f2bf(v);
}

__global__ void pack_xd0(const float* __restrict__ dec, ushort_t* __restrict__ xd) {
  int idx = blockIdx.x * 256 + threadIdx.x;
  if (idx >= BATCH * KX) return;
  int b = idx >> 7, k = idx & 127;
  float v = (k < IN) ? dec[(size_t)b * OSTR + k] : 0.f;
  xd[idx] = f2bf(v);
}

__global__ void pack_fc(const float* __restrict__ fcw, ushort_t* __restrict__ Wfc) {
  int idx = blockIdx.x * 256 + threadIdx.x;
  if (idx >= 80 * HID) return;
  int n = idx >> 11, k = idx & 2047;
  float v = (n < IN) ? fcw[(size_t)n * HID + k] : 0.f;
  Wfc[idx] = f2bf(v);
}

// ---------------- fused GRU step: B-in-LDS, A global->VGPR, 2 blocks/CU ----------
// grid 512 (8 m x 64 n), block 256 (4 waves, 2m x 2n; wave 64 rows x 48 gate-cols).
// Per-CU per-K-step walls: MFMA 932 cyc, LDS-read 565 cyc (B only, 48 KB), VMEM ~600
// (A 16 KB/block unique, L1-served re-reads). Three different pipes + 2 phase-
// decoupled blocks -> MFMA-bound target. A(kt+1)/B(kt+1) issued at iter TOP (full-
// body issue->wait distance); one vmcnt(0)+barrier per iter; K-loop unrolled x2 with
// NAMED A register sets (no runtime-indexed reg arrays).
__global__ __launch_bounds__(256, 2) void gru_step_kernel(
    const ushort_t* __restrict__ x,    // [1024][128] bf16
    const ushort_t* __restrict__ hbp,  // [1024][2048] bf16 h_prev
    const ushort_t* __restrict__ Wp,   // [6144][2176] bf16
    const float*    __restrict__ b_ih,
    const float*    __restrict__ b_hh,
    ushort_t*       __restrict__ hbn)  // [1024][2048] bf16 h_new
{
  __shared__ ushort_t lds[2][96 * BK];   // B tiles only: 12 KB x 2 = 24 KB

  const int tid  = threadIdx.x;
  const int lane = tid & 63;
  const int wid  = tid >> 6;        // 0..3
  const int bid  = blockIdx.x;
  // XCD mapping: bid%8 -> XCD (round-robin dispatch); same-XCD blocks share W panels
  const int xcd   = bid & 7;
  const int idx   = bid >> 3;                     // 0..63
  const int m_grp = idx & 7;                      // 0..7
  const int n_grp = xcd + 8 * (idx >> 3);         // 0..63
  const int row0  = m_grp * 128;
  const int col0  = n_grp * 32;
  const int wm = wid >> 1;          // 0..1 : 64-row half
  const int wn = wid & 1;           // 0..1 : 16-col half (per gate)

  const f32x4 Z4 = {0.f, 0.f, 0.f, 0.f};
  f32x4 accr[4], accz[4], accN[4], accin[4];
  #pragma unroll
  for (int a = 0; a < 4; ++a) { accr[a] = Z4; accz[a] = Z4; accN[a] = Z4; accin[a] = Z4; }

  // B staging constants (proven): chunk = 8 rows x 64 cols (1 KB); row = lane>>3;
  // source 16B-group pre-XORed with (row&7) so linear LDS dest holds swizzled layout
  const int srow  = lane >> 3;
  const int swcol = (((lane & 7) ^ (srow & 7)) << 3);   // elements

  // fragment-read constants (consumer-side XOR, proven)
  const int lr  = lane & 15;
  const int lhi = lane >> 4;                              // 0..3
  const int bc  = lhi * 16;                               // byte col, pre-swizzle
  const int ksw0 = ((bc)      ^ ((lane & 7) << 4)) >> 1;  // element offsets
  const int ksw1 = ((64 + bc) ^ ((lane & 7) << 4)) >> 1;

  auto stageB = [&](int buf, int kt) {
    const int wk0 = kt * BK;
    ushort_t* Lb = &lds[buf][0];
    #pragma unroll
    for (int c = 0; c < 3; ++c) {                 // 3 chunks/wave (12 total = 96 rows)
      const int chunk = wid * 3 + c;              // 0..11
      const int brow = chunk * 8 + srow;          // 0..95 (gate*32 + col)
      const int gg = brow >> 5, wi = brow & 31;
      const ushort_t* g = Wp + (size_t)(gg * HID + col0 + wi) * KP + wk0 + swcol;
      gload_lds16(g, Lb + chunk * 512);
    }
  };

  // A fragments straight from global: frag = 16 rows x (8 bf16), lane l15 = row,
  // lhi = 8-elem k-group — identical content to the proven LDS-read fragment.
  auto loadA = [&](int kt, bf16x8 (&a)[8]) {
    const ushort_t* asrc; int astr, ak0;
    if (kt < 2) { asrc = x;   astr = KX;  ak0 = kt * BK; }
    else        { asrc = hbp; astr = HID; ak0 = (kt - 2) * BK; }
    #pragma unroll
    for (int ks = 0; ks < 2; ++ks)
      #pragma unroll
      for (int fm = 0; fm < 4; ++fm)
        a[ks * 4 + fm] = *reinterpret_cast<const bf16x8*>(
            &asrc[(size_t)(row0 + wm * 64 + fm * 16 + lr) * astr + ak0 + ks * 32 + lhi * 8]);
  };

  auto readB = [&](const ushort_t* Lb, int ko, bf16x8 bg[3]) {
    #pragma unroll
    for (int g = 0; g < 3; ++g)
      bg[g] = *reinterpret_cast<const bf16x8*>(&Lb[(g * 32 + wn * 16 + lr) * BK + ko]);
  };

  auto burst = [&](const bf16x8* af, bf16x8 bg[3]) {
    __builtin_amdgcn_s_setprio(1);
    #pragma unroll
    for (int fm = 0; fm < 4; ++fm) {
      accr[fm] = mfma16(af[fm], bg[0], accr[fm]);
      accz[fm] = mfma16(af[fm], bg[1], accz[fm]);
      accN[fm] = mfma16(af[fm], bg[2], accN[fm]);
    }
    __builtin_amdgcn_s_setprio(0);
  };

  bf16x8 A0[8], A1[8];
  bf16x8 bg0[3], bg1[3];

  auto body = [&](int kt, bf16x8 (&aUse)[8], bf16x8 (&aPre)[8]) {
    if (kt + 1 < KTT) {               // issue next tile's loads at iter TOP
      loadA(kt + 1, aPre);
      stageB((kt + 1) & 1, kt + 1);
    }
    const ushort_t* Lb = &lds[kt & 1][0];
    readB(Lb, ksw0, bg0);
    readB(Lb, ksw1, bg1);
    burst(&aUse[0], bg0);
    burst(&aUse[4], bg1);
    if (kt == 1) {   // k 0..127 (= x tiles) done: capture i_n, restart for h_n
      #pragma unroll
      for (int a = 0; a < 4; ++a) { accin[a] = accN[a]; accN[a] = Z4; }
    }
    if (kt + 1 < KTT) {
      asm volatile("s_waitcnt vmcnt(0)" ::: "memory");  // A(kt+1) + B(kt+1) landed
      __builtin_amdgcn_s_barrier();
    }
  };

  // prologue: tile 0 operands in flight, then landed
  loadA(0, A0);
  stageB(0, 0);
  asm volatile("s_waitcnt vmcnt(0)" ::: "memory");
  __builtin_amdgcn_s_barrier();

  for (int kt = 0; kt < KTT; kt += 2) {
    body(kt,     A0, A1);
    body(kt + 1, A1, A0);
  }

  // epilogue: gates + recurrence, bf16 state
  // C/D layout: col = lane&15, row = (lane>>4)*4 + q
  const int lqb = lhi * 4;
  const int j = col0 + wn * 16 + lr;
  const float br  = b_ih[j] + b_hh[j];
  const float bz  = b_ih[HID + j] + b_hh[HID + j];
  const float bin = b_ih[2 * HID + j];
  const float bhn = b_hh[2 * HID + j];
  #pragma unroll
  for (int fm = 0; fm < 4; ++fm) {
    #pragma unroll
    for (int q = 0; q < 4; ++q) {
      const int row = row0 + wm * 64 + fm * 16 + lqb + q;
      const size_t off = (size_t)row * HID + j;
      const float hp = bf2f(hbp[off]);
      const float rr = sigmoidf_(accr[fm][q] + br);
      const float zz = sigmoidf_(accz[fm][q] + bz);
      const float nn = tanhf_(accin[fm][q] + bin + rr * (accN[fm][q] + bhn));
      const float hv = (1.0f - zz) * nn + zz * hp;
      hbn[off] = f2bf(hv);
    }
  }
}

// ---------------- decoder fc: out = prev + h_new @ fc_w^T + fc_b; also emit next x (bf16) ----
__global__ __launch_bounds__(256) void fc_kernel(
    const ushort_t* __restrict__ hb,    // [1024][2048] bf16 h_new
    const ushort_t* __restrict__ Wfc,   // [80][2048] bf16
    const float*    __restrict__ fc_b,
    const float*    __restrict__ prev,  // row stride OSTR
    float*          __restrict__ outp,  // d_out + t*IN, row stride OSTR
    ushort_t*       __restrict__ xd)    // [1024][128] bf16 next input
{
  __shared__ float red[4][16][80];
  const int tid = threadIdx.x, lane = tid & 63, wid = tid >> 6;
  const int r0 = blockIdx.x * 16;
  const int lr = lane & 15, lk = (lane >> 4) * 8;
  const f32x4 Z4 = {0.f, 0.f, 0.f, 0.f};
  f32x4 acc[5];
  #pragma unroll
  for (int f = 0; f < 5; ++f) acc[f] = Z4;
  const int kbase = wid * 512;
  #pragma unroll
  for (int ks = 0; ks < 16; ++ks) {
    const int k = kbase + ks * 32 + lk;
    bf16x8 a = *reinterpret_cast<const bf16x8*>(&hb[(size_t)(r0 + lr) * HID + k]);
    #pragma unroll
    for (int f = 0; f < 5; ++f) {
      bf16x8 b = *reinterpret_cast<const bf16x8*>(&Wfc[(size_t)(f * 16 + lr) * HID + k]);
      acc[f] = mfma16(a, b, acc[f]);
    }
  }
  #pragma unroll
  for (int f = 0; f < 5; ++f)
    #pragma unroll
    for (int q = 0; q < 4; ++q)
      red[wid][(lane >> 4) * 4 + q][f * 16 + lr] = acc[f][q];
  __syncthreads();

  const int rowi = tid >> 4;          // 0..15
  const int j0   = (tid & 15) * 8;    // 0..120
  const int b_   = r0 + rowi;
  #pragma unroll
  for (int jj = 0; jj < 8; ++jj) {
    const int j = j0 + jj;
    float ov = 0.f;
    if (j < IN) {
      float s = red[0][rowi][j] + red[1][rowi][j] + red[2][rowi][j] + red[3][rowi][j];
      ov = prev[(size_t)b_ * OSTR + j] + fc_b[j] + s;
      outp[(size_t)b_ * OSTR + j] = ov;
    }
    xd[b_ * KX + j] = f2bf(j < IN ? ov : 0.f);
  }
}

// ---------------- host launch ----------------
extern "C" void kernel_launch(void* const* d_in, const int* in_sizes, int n_in,
                              void* d_out, int out_size, void* d_ws, size_t ws_size,
                              hipStream_t stream) {
  const float* enc = (const float*)d_in[0];
  const float* dec = (const float*)d_in[1];
  const float* Wih = (const float*)d_in[2];
  const float* Whh = (const float*)d_in[3];
  const float* bih = (const float*)d_in[4];
  const float* bhh = (const float*)d_in[5];
  const float* fcw = (const float*)d_in[6];
  const float* fcb = (const float*)d_in[7];
  float* out = (float*)d_out;

  char* ws = (char*)d_ws;
  ushort_t* Wp  = (ushort_t*)ws;  ws += (size_t)6144 * KP * 2;          // 26.7 MB
  ushort_t* xe  = (ushort_t*)ws;  ws += (size_t)SENC * BATCH * KX * 2;  // 12.8 MB
  ushort_t* xd  = (ushort_t*)ws;  ws += (size_t)BATCH * KX * 2;         // 256 KB
  ushort_t* Wfc = (ushort_t*)ws;  ws += (size_t)80 * HID * 2;           // 320 KB
  ushort_t* hb0 = (ushort_t*)ws;  ws += (size_t)BATCH * HID * 2;
  ushort_t* hb1 = (ushort_t*)ws;  ws += (size_t)BATCH * HID * 2;
  ushort_t* hbp[2] = {hb0, hb1};

  pack_W  <<<(6144 * KP + 255) / 256, 256, 0, stream>>>(Wih, Whh, Wp);
  pack_xe <<<(SENC * BATCH * KX + 255) / 256, 256, 0, stream>>>(enc, xe);
  pack_xd0<<<(BATCH * KX + 255) / 256, 256, 0, stream>>>(dec, xd);
  pack_fc <<<(80 * HID + 255) / 256, 256, 0, stream>>>(fcw, Wfc);
  hipMemsetAsync(hb0, 0, (size_t)BATCH * HID * 2, stream);

  for (int s = 0; s < SENC + TDEC; ++s) {
    const ushort_t* xsrc = (s < SENC) ? (xe + (size_t)s * BATCH * KX) : xd;
    gru_step_kernel<<<512, 256, 0, stream>>>(xsrc, hbp[s & 1], Wp, bih, bhh,
                                             hbp[(s + 1) & 1]);
    if (s >= SENC) {
      const int t = s - SENC;
      const float* prev = (t == 0) ? dec : (out + (size_t)(t - 1) * IN);
      fc_kernel<<<64, 256, 0, stream>>>(hbp[(s + 1) & 1], Wfc, fcb, prev,
                                        out + (size_t)t * IN, xd);
    }
  }
}

// Round 11
// 3002.644 us; speedup vs baseline: 1.9492x; 1.9492x over previous
//
#include <hip/hip_runtime.h>
#include <cstdint>
#include <cstddef>

#define DI __device__ __forceinline__

typedef __bf16 bf16x8 __attribute__((ext_vector_type(8)));
typedef float  f32x4  __attribute__((ext_vector_type(4)));
typedef unsigned short ushort_t;

constexpr int BATCH = 1024;
constexpr int HID   = 2048;
constexpr int IN    = 76;
constexpr int SENC  = 49;
constexpr int TDEC  = 25;
constexpr int KX    = 128;          // x padded to 128 cols
constexpr int KP    = KX + HID;     // 2176 packed K
constexpr int BK    = 64;           // K-step (one LDS tile)
constexpr int KTT   = KP / BK;      // 34 K-steps
constexpr int OSTR  = TDEC * IN;    // 1900 (row stride of decoder_inputs and d_out)

DI unsigned short f2bf(float f) {
  union { float f; unsigned u; } v; v.f = f;
  unsigned u = v.u;
  return (unsigned short)((u + 0x7fffu + ((u >> 16) & 1u)) >> 16);  // RTNE
}

DI float bf2f(unsigned short h) {
  union { unsigned u; float f; } v; v.u = ((unsigned)h) << 16;
  return v.f;
}

DI f32x4 mfma16(bf16x8 a, bf16x8 b, f32x4 c) {
  return __builtin_amdgcn_mfma_f32_16x16x32_bf16(a, b, c, 0, 0, 0);
}

DI void gload_lds16(const void* g, void* l) {
  __builtin_amdgcn_global_load_lds((const __attribute__((address_space(1))) void*)g,
                                   (__attribute__((address_space(3))) void*)l,
                                   16, 0, 0);
}

DI float sigmoidf_(float x) { return 1.0f / (1.0f + __expf(-x)); }
DI float tanhf_(float x)    { return 1.0f - 2.0f / (1.0f + __expf(2.0f * x)); }

// ---------------- packing kernels (run once per launch) ----------------

__global__ void pack_W(const float* __restrict__ Wih, const float* __restrict__ Whh,
                       ushort_t* __restrict__ Wp) {
  int idx = blockIdx.x * 256 + threadIdx.x;
  if (idx >= 6144 * KP) return;
  int n = idx / KP;
  int k = idx - n * KP;
  float v = 0.f;
  if (k < IN)        v = Wih[(size_t)n * IN + k];
  else if (k >= KX)  v = Whh[(size_t)n * HID + (k - KX)];
  Wp[idx] = f2bf(v);
}

__global__ void pack_xe(const float* __restrict__ enc, ushort_t* __restrict__ xe) {
  int idx = blockIdx.x * 256 + threadIdx.x;
  if (idx >= SENC * BATCH * KX) return;
  int t = idx >> 17;
  int rem = idx & 131071;
  int b = rem >> 7, k = rem & 127;
  float v = (k < IN) ? enc[(size_t)b * (SENC * IN) + t * IN + k] : 0.f;
  xe[idx] = f2bf(v);
}

__global__ void pack_xd0(const float* __restrict__ dec, ushort_t* __restrict__ xd) {
  int idx = blockIdx.x * 256 + threadIdx.x;
  if (idx >= BATCH * KX) return;
  int b = idx >> 7, k = idx & 127;
  float v = (k < IN) ? dec[(size_t)b * OSTR + k] : 0.f;
  xd[idx] = f2bf(v);
}

__global__ void pack_fc(const float* __restrict__ fcw, ushort_t* __restrict__ Wfc) {
  int idx = blockIdx.x * 256 + threadIdx.x;
  if (idx >= 80 * HID) return;
  int n = idx >> 11, k = idx & 2047;
  float v = (n < IN) ? fcw[(size_t)n * HID + k] : 0.f;
  Wfc[idx] = f2bf(v);
}

// ---------------- fused GRU step: 4 blocks/CU, 4 independent barrier domains ----------
// grid 1024 (16 m x 64 n), block 128 (2 waves, 1m x 2n; wave 64 rows x 48 gate-cols —
// the proven R7/R9 per-wave shape). Block tile 64 rows x 32 n-cols; B = 96 Wp rows.
// LDS 2 x 20 KB = 40 KB/block -> FOUR independent blocks per CU (160 KB exactly):
// same per-CU LDS/MFMA walls as R9 (112 reads / 932 cyc per BK64) but 4 phase-
// decoupled barrier groups instead of 2 -> overlap toward max(LDS, MFMA) not sum.
__global__ __launch_bounds__(128, 2) void gru_step_kernel(
    const ushort_t* __restrict__ x,    // [1024][128] bf16
    const ushort_t* __restrict__ hbp,  // [1024][2048] bf16 h_prev
    const ushort_t* __restrict__ Wp,   // [6144][2176] bf16
    const float*    __restrict__ b_ih,
    const float*    __restrict__ b_hh,
    ushort_t*       __restrict__ hbn)  // [1024][2048] bf16 h_new
{
  __shared__ ushort_t lds[2][(64 + 96) * BK];   // A 64x64 + B 96x64 = 20 KB x 2

  const int tid  = threadIdx.x;
  const int lane = tid & 63;
  const int wid  = tid >> 6;        // 0..1
  const int bid  = blockIdx.x;
  // XCD mapping: bid%8 -> XCD (round-robin dispatch); per XCD: 8 n-panels x 16 m ->
  // W per XCD = 8 x 96 x 2176 x 2 = 3.3 MB < 4 MB L2
  const int xcd   = bid & 7;
  const int idx   = bid >> 3;                     // 0..127
  const int m_grp = idx & 15;                     // 0..15
  const int n_grp = xcd + 8 * (idx >> 4);         // 0..63
  const int row0  = m_grp * 64;
  const int col0  = n_grp * 32;
  const int wn = wid;               // 0..1 : 16-col half (per gate)

  const f32x4 Z4 = {0.f, 0.f, 0.f, 0.f};
  f32x4 accr[4], accz[4], accN[4], accin[4];
  #pragma unroll
  for (int a = 0; a < 4; ++a) { accr[a] = Z4; accz[a] = Z4; accN[a] = Z4; accin[a] = Z4; }

  // staging constants (proven): chunk = 8 rows x 64 cols (1 KB); row = lane>>3;
  // source 16B-group pre-XORed with (row&7) so linear LDS dest holds swizzled layout
  const int srow  = lane >> 3;
  const int swcol = (((lane & 7) ^ (srow & 7)) << 3);   // elements

  // fragment-read constants (consumer-side XOR, proven)
  const int lr  = lane & 15;
  const int lhi = lane >> 4;                              // 0..3
  const int bc  = lhi * 16;                               // byte col, pre-swizzle
  const int ksw0 = ((bc)      ^ ((lane & 7) << 4)) >> 1;  // element offsets
  const int ksw1 = ((64 + bc) ^ ((lane & 7) << 4)) >> 1;

  auto stage = [&](int buf, int kt) {
    const ushort_t* asrc; int astr, ak0;
    if (kt < 2) { asrc = x;   astr = KX;  ak0 = kt * BK; }
    else        { asrc = hbp; astr = HID; ak0 = (kt - 2) * BK; }
    ushort_t* Lb = &lds[buf][0];
    #pragma unroll
    for (int c = 0; c < 4; ++c) {                 // A: 4 chunks/wave (8 total = 64 rows)
      const int chunk = wid * 4 + c;              // 0..7
      const ushort_t* g = asrc + (size_t)(row0 + chunk * 8 + srow) * astr + ak0 + swcol;
      gload_lds16(g, Lb + chunk * 512);
    }
    const int wk0 = kt * BK;
    #pragma unroll
    for (int c = 0; c < 6; ++c) {                 // B: 6 chunks/wave (12 total = 96 rows)
      const int chunk = wid * 6 + c;              // 0..11
      const int brow = chunk * 8 + srow;          // 0..95 (gate*32 + col)
      const int gg = brow >> 5, wi = brow & 31;
      const ushort_t* g = Wp + (size_t)(gg * HID + col0 + wi) * KP + wk0 + swcol;
      gload_lds16(g, Lb + 64 * BK + chunk * 512);
    }
  };

  auto readFrags = [&](const ushort_t* base, int ko, bf16x8 af[4], bf16x8 bg[3]) {
    #pragma unroll
    for (int fm = 0; fm < 4; ++fm)
      af[fm] = *reinterpret_cast<const bf16x8*>(&base[(fm * 16 + lr) * BK + ko]);
    #pragma unroll
    for (int g = 0; g < 3; ++g)
      bg[g] = *reinterpret_cast<const bf16x8*>(
          &base[64 * BK + (g * 32 + wn * 16 + lr) * BK + ko]);
  };

  auto burst = [&](bf16x8 af[4], bf16x8 bg[3]) {
    __builtin_amdgcn_s_setprio(1);
    #pragma unroll
    for (int fm = 0; fm < 4; ++fm) {
      accr[fm] = mfma16(af[fm], bg[0], accr[fm]);
      accz[fm] = mfma16(af[fm], bg[1], accz[fm]);
      accN[fm] = mfma16(af[fm], bg[2], accN[fm]);
    }
    __builtin_amdgcn_s_setprio(0);
  };

  bf16x8 afA[4], bgA[3];   // ks0 set
  bf16x8 afB[4], bgB[3];   // ks1 set

  // prologue: tile 0 staged and landed
  stage(0, 0);
  asm volatile("s_waitcnt vmcnt(0)" ::: "memory");
  __builtin_amdgcn_s_barrier();

  for (int kt = 0; kt < KTT; ++kt) {
    const ushort_t* base = &lds[kt & 1][0];
    if (kt + 1 < KTT) stage((kt + 1) & 1, kt + 1);   // into the half freed by iter kt-1
    readFrags(base, ksw0, afA, bgA);
    readFrags(base, ksw1, afB, bgB);                 // in flight under burst A
    burst(afA, bgA);
    burst(afB, bgB);

    if (kt == 1) {   // k 0..127 (= x tiles) done: capture i_n, restart for h_n
      #pragma unroll
      for (int a = 0; a < 4; ++a) { accin[a] = accN[a]; accN[a] = Z4; }
    }

    if (kt + 1 < KTT) {
      asm volatile("s_waitcnt vmcnt(0)" ::: "memory");  // tile kt+1 landed
      __builtin_amdgcn_s_barrier();
    }
  }

  // epilogue: gates + recurrence, bf16 state
  // C/D layout: col = lane&15, row = (lane>>4)*4 + q
  const int lqb = lhi * 4;
  const int j = col0 + wn * 16 + lr;
  const float br  = b_ih[j] + b_hh[j];
  const float bz  = b_ih[HID + j] + b_hh[HID + j];
  const float bin = b_ih[2 * HID + j];
  const float bhn = b_hh[2 * HID + j];
  #pragma unroll
  for (int fm = 0; fm < 4; ++fm) {
    #pragma unroll
    for (int q = 0; q < 4; ++q) {
      const int row = row0 + fm * 16 + lqb + q;
      const size_t off = (size_t)row * HID + j;
      const float hp = bf2f(hbp[off]);
      const float rr = sigmoidf_(accr[fm][q] + br);
      const float zz = sigmoidf_(accz[fm][q] + bz);
      const float nn = tanhf_(accin[fm][q] + bin + rr * (accN[fm][q] + bhn));
      const float hv = (1.0f - zz) * nn + zz * hp;
      hbn[off] = f2bf(hv);
    }
  }
}

// ---------------- decoder fc: out = prev + h_new @ fc_w^T + fc_b; also emit next x ----
// 64 blocks x 512 threads (8 waves, 8-way K-split of K=2048 -> 256 k/wave)
__global__ __launch_bounds__(512) void fc_kernel(
    const ushort_t* __restrict__ hb,    // [1024][2048] bf16 h_new
    const ushort_t* __restrict__ Wfc,   // [80][2048] bf16
    const float*    __restrict__ fc_b,
    const float*    __restrict__ prev,  // row stride OSTR
    float*          __restrict__ outp,  // d_out + t*IN, row stride OSTR
    ushort_t*       __restrict__ xd)    // [1024][128] bf16 next input
{
  __shared__ float red[8][16][80];
  const int tid = threadIdx.x, lane = tid & 63, wid = tid >> 6;   // wid 0..7
  const int r0 = blockIdx.x * 16;
  const int lr = lane & 15, lk = (lane >> 4) * 8;
  const f32x4 Z4 = {0.f, 0.f, 0.f, 0.f};
  f32x4 acc[5];
  #pragma unroll
  for (int f = 0; f < 5; ++f) acc[f] = Z4;
  const int kbase = wid * 256;
  #pragma unroll
  for (int ks = 0; ks < 8; ++ks) {
    const int k = kbase + ks * 32 + lk;
    bf16x8 a = *reinterpret_cast<const bf16x8*>(&hb[(size_t)(r0 + lr) * HID + k]);
    #pragma unroll
    for (int f = 0; f < 5; ++f) {
      bf16x8 b = *reinterpret_cast<const bf16x8*>(&Wfc[(size_t)(f * 16 + lr) * HID + k]);
      acc[f] = mfma16(a, b, acc[f]);
    }
  }
  #pragma unroll
  for (int f = 0; f < 5; ++f)
    #pragma unroll
    for (int q = 0; q < 4; ++q)
      red[wid][(lane >> 4) * 4 + q][f * 16 + lr] = acc[f][q];
  __syncthreads();

  if (tid < 256) {
    const int rowi = tid >> 4;          // 0..15
    const int j0   = (tid & 15) * 8;    // 0..120
    const int b_   = r0 + rowi;
    #pragma unroll
    for (int jj = 0; jj < 8; ++jj) {
      const int j = j0 + jj;
      float ov = 0.f;
      if (j < IN) {
        float s = 0.f;
        #pragma unroll
        for (int w = 0; w < 8; ++w) s += red[w][rowi][j];
        ov = prev[(size_t)b_ * OSTR + j] + fc_b[j] + s;
        outp[(size_t)b_ * OSTR + j] = ov;
      }
      xd[b_ * KX + j] = f2bf(j < IN ? ov : 0.f);
    }
  }
}

// ---------------- host launch ----------------
extern "C" void kernel_launch(void* const* d_in, const int* in_sizes, int n_in,
                              void* d_out, int out_size, void* d_ws, size_t ws_size,
                              hipStream_t stream) {
  const float* enc = (const float*)d_in[0];
  const float* dec = (const float*)d_in[1];
  const float* Wih = (const float*)d_in[2];
  const float* Whh = (const float*)d_in[3];
  const float* bih = (const float*)d_in[4];
  const float* bhh = (const float*)d_in[5];
  const float* fcw = (const float*)d_in[6];
  const float* fcb = (const float*)d_in[7];
  float* out = (float*)d_out;

  char* ws = (char*)d_ws;
  ushort_t* Wp  = (ushort_t*)ws;  ws += (size_t)6144 * KP * 2;          // 26.7 MB
  ushort_t* xe  = (ushort_t*)ws;  ws += (size_t)SENC * BATCH * KX * 2;  // 12.8 MB
  ushort_t* xd  = (ushort_t*)ws;  ws += (size_t)BATCH * KX * 2;         // 256 KB
  ushort_t* Wfc = (ushort_t*)ws;  ws += (size_t)80 * HID * 2;           // 320 KB
  ushort_t* hb0 = (ushort_t*)ws;  ws += (size_t)BATCH * HID * 2;
  ushort_t* hb1 = (ushort_t*)ws;  ws += (size_t)BATCH * HID * 2;
  ushort_t* hbp[2] = {hb0, hb1};

  pack_W  <<<(6144 * KP + 255) / 256, 256, 0, stream>>>(Wih, Whh, Wp);
  pack_xe <<<(SENC * BATCH * KX + 255) / 256, 256, 0, stream>>>(enc, xe);
  pack_xd0<<<(BATCH * KX + 255) / 256, 256, 0, stream>>>(dec, xd);
  pack_fc <<<(80 * HID + 255) / 256, 256, 0, stream>>>(fcw, Wfc);
  hipMemsetAsync(hb0, 0, (size_t)BATCH * HID * 2, stream);

  for (int s = 0; s < SENC + TDEC; ++s) {
    const ushort_t* xsrc = (s < SENC) ? (xe + (size_t)s * BATCH * KX) : xd;
    gru_step_kernel<<<1024, 128, 0, stream>>>(xsrc, hbp[s & 1], Wp, bih, bhh,
                                              hbp[(s + 1) & 1]);
    if (s >= SENC) {
      const int t = s - SENC;
      const float* prev = (t == 0) ? dec : (out + (size_t)(t - 1) * IN);
      fc_kernel<<<64, 512, 0, stream>>>(hbp[(s + 1) & 1], Wfc, fcb, prev,
                                        out + (size_t)t * IN, xd);
    }
  }
}

// Round 12
// 2856.695 us; speedup vs baseline: 2.0488x; 1.0511x over previous
//
#include <hip/hip_runtime.h>
#include <cstdint>
#include <cstddef>

#define DI __device__ __forceinline__

typedef __bf16 bf16x8 __attribute__((ext_vector_type(8)));
typedef float  f32x4  __attribute__((ext_vector_type(4)));
typedef unsigned short ushort_t;

constexpr int BATCH = 1024;
constexpr int HID   = 2048;
constexpr int IN    = 76;
constexpr int SENC  = 49;
constexpr int TDEC  = 25;
constexpr int KX    = 128;          // x padded to 128 cols
constexpr int KP    = KX + HID;     // 2176 packed K
constexpr int BK    = 64;           // K-step
constexpr int KTT   = KP / BK;      // 34 K-steps (even -> unroll-by-2)
constexpr int NKT32 = KP / 32;      // 68 k-tiles of 32 (fragment granularity)
constexpr int OSTR  = TDEC * IN;    // 1900

DI unsigned short f2bf(float f) {
  union { float f; unsigned u; } v; v.f = f;
  unsigned u = v.u;
  return (unsigned short)((u + 0x7fffu + ((u >> 16) & 1u)) >> 16);  // RTNE
}

DI float bf2f(unsigned short h) {
  union { unsigned u; float f; } v; v.u = ((unsigned)h) << 16;
  return v.f;
}

DI f32x4 mfma16(bf16x8 a, bf16x8 b, f32x4 c) {
  return __builtin_amdgcn_mfma_f32_16x16x32_bf16(a, b, c, 0, 0, 0);
}

DI void gload_lds16(const void* g, void* l) {
  __builtin_amdgcn_global_load_lds((const __attribute__((address_space(1))) void*)g,
                                   (__attribute__((address_space(3))) void*)l,
                                   16, 0, 0);
}

DI float sigmoidf_(float x) { return 1.0f / (1.0f + __expf(-x)); }
DI float tanhf_(float x)    { return 1.0f - 2.0f / (1.0f + __expf(2.0f * x)); }

// ---------------- packing kernels (run once per launch) ----------------

// Wf: W packed in MFMA-B-fragment order. Fragment (NT, KT) covers gate-cols
// [NT*16, NT*16+16) x k [KT*32, KT*32+32); 512 bf16 stored as lane*8+e with
// lane holding col = NT*16 + (lane&15), k = KT*32 + (lane>>4)*8 + e.
// A B-frag load is then ONE coalesced 1KB global_load_dwordx4 (base + lane*16).
__global__ void pack_Wf(const float* __restrict__ Wih, const float* __restrict__ Whh,
                        ushort_t* __restrict__ Wf) {
  int idx = blockIdx.x * 256 + threadIdx.x;
  if (idx >= 6144 * KP) return;
  int fid  = idx >> 9;           // fragment id
  int el   = idx & 511;
  int lane = el >> 3;
  int e    = el & 7;
  int nt   = fid / NKT32;        // 0..383
  int ktl  = fid - nt * NKT32;   // 0..67
  int n    = nt * 16 + (lane & 15);
  int k    = ktl * 32 + (lane >> 4) * 8 + e;
  float v = 0.f;
  if (k < IN)        v = Wih[(size_t)n * IN + k];
  else if (k >= KX)  v = Whh[(size_t)n * HID + (k - KX)];
  Wf[idx] = f2bf(v);
}

__global__ void pack_xe(const float* __restrict__ enc, ushort_t* __restrict__ xe) {
  int idx = blockIdx.x * 256 + threadIdx.x;
  if (idx >= SENC * BATCH * KX) return;
  int t = idx >> 17;
  int rem = idx & 131071;
  int b = rem >> 7, k = rem & 127;
  float v = (k < IN) ? enc[(size_t)b * (SENC * IN) + t * IN + k] : 0.f;
  xe[idx] = f2bf(v);
}

__global__ void pack_xd0(const float* __restrict__ dec, ushort_t* __restrict__ xd) {
  int idx = blockIdx.x * 256 + threadIdx.x;
  if (idx >= BATCH * KX) return;
  int b = idx >> 7, k = idx & 127;
  float v = (k < IN) ? dec[(size_t)b * OSTR + k] : 0.f;
  xd[idx] = f2bf(v);
}

__global__ void pack_fc(const float* __restrict__ fcw, ushort_t* __restrict__ Wfc) {
  int idx = blockIdx.x * 256 + threadIdx.x;
  if (idx >= 80 * HID) return;
  int n = idx >> 11, k = idx & 2047;
  float v = (n < IN) ? fcw[(size_t)n * HID + k] : 0.f;
  Wfc[idx] = f2bf(v);
}

// ---------------- fused GRU step: A-only LDS, B fragment-direct from L2 ----------
// grid 512 (8 m x 64 n), block 256 (4 waves, 2m x 2n; wave 64r x 48gc), 2 blocks/CU.
// LDS carries A only (16 KB dbuf x2 = 32 KB): per-CU LDS reads 64 KB/BK64 = 753 cyc
// < MFMA 932. B comes straight from Wf as coalesced 1KB fragment loads (L2-resident
// panel, 3.3 MB/XCD), prefetched ONE FULL ITERATION ahead into named register sets.
// One vmcnt(0)+barrier per iter (issue->wait = full body). Three pipes balanced.
__global__ __launch_bounds__(256, 2) void gru_step_kernel(
    const ushort_t* __restrict__ x,    // [1024][128] bf16
    const ushort_t* __restrict__ hbp,  // [1024][2048] bf16 h_prev
    const ushort_t* __restrict__ Wf,   // fragment-ordered W (384 x 68 frags)
    const float*    __restrict__ b_ih,
    const float*    __restrict__ b_hh,
    ushort_t*       __restrict__ hbn)  // [1024][2048] bf16 h_new
{
  __shared__ ushort_t lds[2][128 * BK];   // A tiles only: 16 KB x 2

  const int tid  = threadIdx.x;
  const int lane = tid & 63;
  const int wid  = tid >> 6;        // 0..3
  const int bid  = blockIdx.x;
  // XCD mapping: bid%8 -> XCD; same-XCD blocks share 8 n-panels (3.3 MB < 4 MB L2)
  const int xcd   = bid & 7;
  const int idx   = bid >> 3;                     // 0..63
  const int m_grp = idx & 7;                      // 0..7
  const int n_grp = xcd + 8 * (idx >> 3);         // 0..63
  const int row0  = m_grp * 128;
  const int col0  = n_grp * 32;
  const int wm = wid >> 1;          // 0..1 : 64-row half
  const int wn = wid & 1;           // 0..1 : 16-col half (per gate)
  const int NTb = n_grp * 2 + wn;   // fragment n-tile base (g adds g*128)

  const f32x4 Z4 = {0.f, 0.f, 0.f, 0.f};
  f32x4 accr[4], accz[4], accN[4], accin[4];
  #pragma unroll
  for (int a = 0; a < 4; ++a) { accr[a] = Z4; accz[a] = Z4; accN[a] = Z4; accin[a] = Z4; }

  // A staging constants (proven): chunk = 8 rows x 64 cols (1 KB); row = lane>>3;
  // source 16B-group pre-XORed with (row&7); reader applies identical XOR
  const int srow  = lane >> 3;
  const int swcol = (((lane & 7) ^ (srow & 7)) << 3);   // elements

  const int lr  = lane & 15;
  const int lhi = lane >> 4;
  const int bc  = lhi * 16;
  const int ksw0 = ((bc)      ^ ((lane & 7) << 4)) >> 1;
  const int ksw1 = ((64 + bc) ^ ((lane & 7) << 4)) >> 1;

  auto stageA = [&](int buf, int kt) {
    const ushort_t* asrc; int astr, ak0;
    if (kt < 2) { asrc = x;   astr = KX;  ak0 = kt * BK; }
    else        { asrc = hbp; astr = HID; ak0 = (kt - 2) * BK; }
    ushort_t* Lb = &lds[buf][0];
    #pragma unroll
    for (int c = 0; c < 4; ++c) {                 // 4 chunks/wave (16 total = 128 rows)
      const int chunk = wid * 4 + c;              // 0..15
      const ushort_t* g = asrc + (size_t)(row0 + chunk * 8 + srow) * astr + ak0 + swcol;
      gload_lds16(g, Lb + chunk * 512);
    }
  };

  // B fragment loads: 6 per BK64 (3 gates x 2 ks), each ONE coalesced 1KB load
  auto loadB = [&](int kt, bf16x8 (&bg)[6]) {
    #pragma unroll
    for (int g = 0; g < 3; ++g)
      #pragma unroll
      for (int ks = 0; ks < 2; ++ks) {
        const size_t fo = ((size_t)((g * 128 + NTb) * NKT32 + (kt * 2 + ks))) << 9;
        bg[g * 2 + ks] = *reinterpret_cast<const bf16x8*>(Wf + fo + lane * 8);
      }
  };

  auto readA = [&](const ushort_t* base, int ko, bf16x8 af[4]) {
    #pragma unroll
    for (int fm = 0; fm < 4; ++fm)
      af[fm] = *reinterpret_cast<const bf16x8*>(&base[(wm * 64 + fm * 16 + lr) * BK + ko]);
  };

  auto burst = [&](bf16x8 af[4], bf16x8 br, bf16x8 bz, bf16x8 bn) {
    __builtin_amdgcn_s_setprio(1);
    #pragma unroll
    for (int fm = 0; fm < 4; ++fm) {
      accr[fm] = mfma16(af[fm], br, accr[fm]);
      accz[fm] = mfma16(af[fm], bz, accz[fm]);
      accN[fm] = mfma16(af[fm], bn, accN[fm]);
    }
    __builtin_amdgcn_s_setprio(0);
  };

  bf16x8 B0[6], B1[6];
  bf16x8 afA[4], afB[4];

  // prologue: tile-0 operands issued and landed
  loadB(0, B0);
  stageA(0, 0);
  asm volatile("s_waitcnt vmcnt(0)" ::: "memory");
  __builtin_amdgcn_s_barrier();

  auto body = [&](int kt, bf16x8 (&Bc)[6], bf16x8 (&Bn)[6]) {
    if (kt + 1 < KTT) {                 // issue next tile's operands at iter TOP
      loadB(kt + 1, Bn);
      stageA((kt + 1) & 1, kt + 1);
    }
    const ushort_t* base = &lds[kt & 1][0];
    readA(base, ksw0, afA);
    readA(base, ksw1, afB);             // in flight under burst ks0
    burst(afA, Bc[0], Bc[2], Bc[4]);    // ks0: frags g*2+0
    burst(afB, Bc[1], Bc[3], Bc[5]);    // ks1: frags g*2+1
    if (kt == 1) {   // k 0..127 (= x tiles) done: capture i_n, restart for h_n
      #pragma unroll
      for (int a = 0; a < 4; ++a) { accin[a] = accN[a]; accN[a] = Z4; }
    }
    if (kt + 1 < KTT) {
      asm volatile("s_waitcnt vmcnt(0)" ::: "memory");  // next A staged + B landed
      __builtin_amdgcn_s_barrier();
    }
  };

  for (int kt = 0; kt < KTT; kt += 2) {
    body(kt,     B0, B1);
    body(kt + 1, B1, B0);
  }

  // epilogue: gates + recurrence, bf16 state
  // C/D layout: col = lane&15, row = (lane>>4)*4 + q
  const int lqb = lhi * 4;
  const int j = col0 + wn * 16 + lr;
  const float br  = b_ih[j] + b_hh[j];
  const float bz  = b_ih[HID + j] + b_hh[HID + j];
  const float bin = b_ih[2 * HID + j];
  const float bhn = b_hh[2 * HID + j];
  #pragma unroll
  for (int fm = 0; fm < 4; ++fm) {
    #pragma unroll
    for (int q = 0; q < 4; ++q) {
      const int row = row0 + wm * 64 + fm * 16 + lqb + q;
      const size_t off = (size_t)row * HID + j;
      const float hp = bf2f(hbp[off]);
      const float rr = sigmoidf_(accr[fm][q] + br);
      const float zz = sigmoidf_(accz[fm][q] + bz);
      const float nn = tanhf_(accin[fm][q] + bin + rr * (accN[fm][q] + bhn));
      const float hv = (1.0f - zz) * nn + zz * hp;
      hbn[off] = f2bf(hv);
    }
  }
}

// ---------------- decoder fc: out = prev + h_new @ fc_w^T + fc_b; also emit next x ----
__global__ __launch_bounds__(512) void fc_kernel(
    const ushort_t* __restrict__ hb,    // [1024][2048] bf16 h_new
    const ushort_t* __restrict__ Wfc,   // [80][2048] bf16
    const float*    __restrict__ fc_b,
    const float*    __restrict__ prev,  // row stride OSTR
    float*          __restrict__ outp,  // d_out + t*IN, row stride OSTR
    ushort_t*       __restrict__ xd)    // [1024][128] bf16 next input
{
  __shared__ float red[8][16][80];
  const int tid = threadIdx.x, lane = tid & 63, wid = tid >> 6;   // wid 0..7
  const int r0 = blockIdx.x * 16;
  const int lr = lane & 15, lk = (lane >> 4) * 8;
  const f32x4 Z4 = {0.f, 0.f, 0.f, 0.f};
  f32x4 acc[5];
  #pragma unroll
  for (int f = 0; f < 5; ++f) acc[f] = Z4;
  const int kbase = wid * 256;
  #pragma unroll
  for (int ks = 0; ks < 8; ++ks) {
    const int k = kbase + ks * 32 + lk;
    bf16x8 a = *reinterpret_cast<const bf16x8*>(&hb[(size_t)(r0 + lr) * HID + k]);
    #pragma unroll
    for (int f = 0; f < 5; ++f) {
      bf16x8 b = *reinterpret_cast<const bf16x8*>(&Wfc[(size_t)(f * 16 + lr) * HID + k]);
      acc[f] = mfma16(a, b, acc[f]);
    }
  }
  #pragma unroll
  for (int f = 0; f < 5; ++f)
    #pragma unroll
    for (int q = 0; q < 4; ++q)
      red[wid][(lane >> 4) * 4 + q][f * 16 + lr] = acc[f][q];
  __syncthreads();

  if (tid < 256) {
    const int rowi = tid >> 4;          // 0..15
    const int j0   = (tid & 15) * 8;    // 0..120
    const int b_   = r0 + rowi;
    #pragma unroll
    for (int jj = 0; jj < 8; ++jj) {
      const int j = j0 + jj;
      float ov = 0.f;
      if (j < IN) {
        float s = 0.f;
        #pragma unroll
        for (int w = 0; w < 8; ++w) s += red[w][rowi][j];
        ov = prev[(size_t)b_ * OSTR + j] + fc_b[j] + s;
        outp[(size_t)b_ * OSTR + j] = ov;
      }
      xd[b_ * KX + j] = f2bf(j < IN ? ov : 0.f);
    }
  }
}

// ---------------- host launch ----------------
extern "C" void kernel_launch(void* const* d_in, const int* in_sizes, int n_in,
                              void* d_out, int out_size, void* d_ws, size_t ws_size,
                              hipStream_t stream) {
  const float* enc = (const float*)d_in[0];
  const float* dec = (const float*)d_in[1];
  const float* Wih = (const float*)d_in[2];
  const float* Whh = (const float*)d_in[3];
  const float* bih = (const float*)d_in[4];
  const float* bhh = (const float*)d_in[5];
  const float* fcw = (const float*)d_in[6];
  const float* fcb = (const float*)d_in[7];
  float* out = (float*)d_out;

  char* ws = (char*)d_ws;
  ushort_t* Wf  = (ushort_t*)ws;  ws += (size_t)6144 * KP * 2;          // 26.7 MB
  ushort_t* xe  = (ushort_t*)ws;  ws += (size_t)SENC * BATCH * KX * 2;  // 12.8 MB
  ushort_t* xd  = (ushort_t*)ws;  ws += (size_t)BATCH * KX * 2;         // 256 KB
  ushort_t* Wfc = (ushort_t*)ws;  ws += (size_t)80 * HID * 2;           // 320 KB
  ushort_t* hb0 = (ushort_t*)ws;  ws += (size_t)BATCH * HID * 2;
  ushort_t* hb1 = (ushort_t*)ws;  ws += (size_t)BATCH * HID * 2;
  ushort_t* hbp[2] = {hb0, hb1};

  pack_Wf <<<(6144 * KP + 255) / 256, 256, 0, stream>>>(Wih, Whh, Wf);
  pack_xe <<<(SENC * BATCH * KX + 255) / 256, 256, 0, stream>>>(enc, xe);
  pack_xd0<<<(BATCH * KX + 255) / 256, 256, 0, stream>>>(dec, xd);
  pack_fc <<<(80 * HID + 255) / 256, 256, 0, stream>>>(fcw, Wfc);
  hipMemsetAsync(hb0, 0, (size_t)BATCH * HID * 2, stream);

  for (int s = 0; s < SENC + TDEC; ++s) {
    const ushort_t* xsrc = (s < SENC) ? (xe + (size_t)s * BATCH * KX) : xd;
    gru_step_kernel<<<512, 256, 0, stream>>>(xsrc, hbp[s & 1], Wf, bih, bhh,
                                             hbp[(s + 1) & 1]);
    if (s >= SENC) {
      const int t = s - SENC;
      const float* prev = (t == 0) ? dec : (out + (size_t)(t - 1) * IN);
      fc_kernel<<<64, 512, 0, stream>>>(hbp[(s + 1) & 1], Wfc, fcb, prev,
                                        out + (size_t)t * IN, xd);
    }
  }
}

// Round 13
// 2660.206 us; speedup vs baseline: 2.2001x; 1.0739x over previous
//
#include <hip/hip_runtime.h>
#include <cstdint>
#include <cstddef>

#define DI __device__ __forceinline__

typedef __bf16 bf16x8 __attribute__((ext_vector_type(8)));
typedef float  f32x4  __attribute__((ext_vector_type(4)));
typedef unsigned short ushort_t;

constexpr int BATCH = 1024;
constexpr int HID   = 2048;
constexpr int IN    = 76;
constexpr int SENC  = 49;
constexpr int TDEC  = 25;
constexpr int KX    = 128;          // x padded to 128 cols
constexpr int KP    = KX + HID;     // 2176 packed K
constexpr int BK    = 64;           // K-step (one LDS tile)
constexpr int KTT   = KP / BK;      // 34 K-steps
constexpr int OSTR  = TDEC * IN;    // 1900 (row stride of decoder_inputs and d_out)

DI unsigned short f2bf(float f) {
  union { float f; unsigned u; } v; v.f = f;
  unsigned u = v.u;
  return (unsigned short)((u + 0x7fffu + ((u >> 16) & 1u)) >> 16);  // RTNE
}

DI float bf2f(unsigned short h) {
  union { unsigned u; float f; } v; v.u = ((unsigned)h) << 16;
  return v.f;
}

DI f32x4 mfma16(bf16x8 a, bf16x8 b, f32x4 c) {
  return __builtin_amdgcn_mfma_f32_16x16x32_bf16(a, b, c, 0, 0, 0);
}

DI void gload_lds16(const void* g, void* l) {
  __builtin_amdgcn_global_load_lds((const __attribute__((address_space(1))) void*)g,
                                   (__attribute__((address_space(3))) void*)l,
                                   16, 0, 0);
}

DI float sigmoidf_(float x) { return 1.0f / (1.0f + __expf(-x)); }
DI float tanhf_(float x)    { return 1.0f - 2.0f / (1.0f + __expf(2.0f * x)); }

// ---------------- packing kernels (run once per launch) ----------------

__global__ void pack_W(const float* __restrict__ Wih, const float* __restrict__ Whh,
                       ushort_t* __restrict__ Wp) {
  int idx = blockIdx.x * 256 + threadIdx.x;
  if (idx >= 6144 * KP) return;
  int n = idx / KP;
  int k = idx - n * KP;
  float v = 0.f;
  if (k < IN)        v = Wih[(size_t)n * IN + k];
  else if (k >= KX)  v = Whh[(size_t)n * HID + (k - KX)];
  Wp[idx] = f2bf(v);
}

__global__ void pack_xe(const float* __restrict__ enc, ushort_t* __restrict__ xe) {
  int idx = blockIdx.x * 256 + threadIdx.x;
  if (idx >= SENC * BATCH * KX) return;
  int t = idx >> 17;
  int rem = idx & 131071;
  int b = rem >> 7, k = rem & 127;
  float v = (k < IN) ? enc[(size_t)b * (SENC * IN) + t * IN + k] : 0.f;
  xe[idx] = f2bf(v);
}

__global__ void pack_xd0(const float* __restrict__ dec, ushort_t* __restrict__ xd) {
  int idx = blockIdx.x * 256 + threadIdx.x;
  if (idx >= BATCH * KX) return;
  int b = idx >> 7, k = idx & 127;
  float v = (k < IN) ? dec[(size_t)b * OSTR + k] : 0.f;
  xd[idx] = f2bf(v);
}

__global__ void pack_fc(const float* __restrict__ fcw, ushort_t* __restrict__ Wfc) {
  int idx = blockIdx.x * 256 + threadIdx.x;
  if (idx >= 80 * HID) return;
  int n = idx >> 11, k = idx & 2047;
  float v = (n < IN) ? fcw[(size_t)n * HID + k] : 0.f;
  Wfc[idx] = f2bf(v);
}

// ---------------- fused GRU step: R9 skeleton + post-barrier second burst ----------
// grid 512 (8 m x 64 n), block 256 (4 waves, 2m x 2n; wave 64 rows x 48 gate-cols).
// Per-block tile 128 rows x 32 n-cols; B = 96 Wp rows; LDS 2 x 28 KB; 2 blocks/CU.
// Per iter: stage(next) -> reads(ks0,ks1) -> burstA -> lgkmcnt(0) -> vmcnt(0) ->
// barrier -> [sched_barrier] burstB. burstB (register-only) executes while other
// waves issue next-iter stage/reads -> MFMA work staggered across the barrier.
__global__ __launch_bounds__(256, 2) void gru_step_kernel(
    const ushort_t* __restrict__ x,    // [1024][128] bf16
    const ushort_t* __restrict__ hbp,  // [1024][2048] bf16 h_prev
    const ushort_t* __restrict__ Wp,   // [6144][2176] bf16
    const float*    __restrict__ b_ih,
    const float*    __restrict__ b_hh,
    ushort_t*       __restrict__ hbn)  // [1024][2048] bf16 h_new
{
  __shared__ ushort_t lds[2][(128 + 96) * BK];   // A 128x64 + B 96x64 = 28 KB x 2

  const int tid  = threadIdx.x;
  const int lane = tid & 63;
  const int wid  = tid >> 6;        // 0..3
  const int bid  = blockIdx.x;
  // XCD mapping: bid%8 -> XCD (round-robin dispatch); same-XCD blocks share 8 W panels
  const int xcd   = bid & 7;
  const int idx   = bid >> 3;                     // 0..63
  const int m_grp = idx & 7;                      // 0..7
  const int n_grp = xcd + 8 * (idx >> 3);         // 0..63
  const int row0  = m_grp * 128;
  const int col0  = n_grp * 32;
  const int wm = wid >> 1;          // 0..1 : 64-row half
  const int wn = wid & 1;           // 0..1 : 16-col half (per gate)

  const f32x4 Z4 = {0.f, 0.f, 0.f, 0.f};
  f32x4 accr[4], accz[4], accN[4], accin[4];
  #pragma unroll
  for (int a = 0; a < 4; ++a) { accr[a] = Z4; accz[a] = Z4; accN[a] = Z4; accin[a] = Z4; }

  // staging constants (proven): chunk = 8 rows x 64 cols (1 KB); row = lane>>3;
  // source 16B-group pre-XORed with (row&7) so linear LDS dest holds swizzled layout
  const int srow  = lane >> 3;
  const int swcol = (((lane & 7) ^ (srow & 7)) << 3);   // elements

  // fragment-read constants (consumer-side XOR, proven)
  const int lr  = lane & 15;
  const int lhi = lane >> 4;
  const int bc  = lhi * 16;                               // byte col, pre-swizzle
  const int ksw0 = ((bc)      ^ ((lane & 7) << 4)) >> 1;  // element offsets
  const int ksw1 = ((64 + bc) ^ ((lane & 7) << 4)) >> 1;

  auto stage = [&](int buf, int kt) {
    const ushort_t* asrc; int astr, ak0;
    if (kt < 2) { asrc = x;   astr = KX;  ak0 = kt * BK; }
    else        { asrc = hbp; astr = HID; ak0 = (kt - 2) * BK; }
    ushort_t* Lb = &lds[buf][0];
    #pragma unroll
    for (int c = 0; c < 4; ++c) {                 // A: 4 chunks/wave (16 total = 128 rows)
      const int chunk = wid * 4 + c;              // 0..15
      const ushort_t* g = asrc + (size_t)(row0 + chunk * 8 + srow) * astr + ak0 + swcol;
      gload_lds16(g, Lb + chunk * 512);
    }
    const int wk0 = kt * BK;
    #pragma unroll
    for (int c = 0; c < 3; ++c) {                 // B: 3 chunks/wave (12 total = 96 rows)
      const int chunk = wid * 3 + c;              // 0..11
      const int brow = chunk * 8 + srow;          // 0..95 (gate*32 + col)
      const int gg = brow >> 5, wi = brow & 31;
      const ushort_t* g = Wp + (size_t)(gg * HID + col0 + wi) * KP + wk0 + swcol;
      gload_lds16(g, Lb + 128 * BK + chunk * 512);
    }
  };

  auto readFrags = [&](const ushort_t* base, int ko, bf16x8 af[4], bf16x8 bg[3]) {
    #pragma unroll
    for (int fm = 0; fm < 4; ++fm)
      af[fm] = *reinterpret_cast<const bf16x8*>(&base[(wm * 64 + fm * 16 + lr) * BK + ko]);
    #pragma unroll
    for (int g = 0; g < 3; ++g)
      bg[g] = *reinterpret_cast<const bf16x8*>(
          &base[128 * BK + (g * 32 + wn * 16 + lr) * BK + ko]);
  };

  auto burst = [&](bf16x8 af[4], bf16x8 bg[3]) {
    __builtin_amdgcn_s_setprio(1);
    #pragma unroll
    for (int fm = 0; fm < 4; ++fm) {
      accr[fm] = mfma16(af[fm], bg[0], accr[fm]);
      accz[fm] = mfma16(af[fm], bg[1], accz[fm]);
      accN[fm] = mfma16(af[fm], bg[2], accN[fm]);
    }
    __builtin_amdgcn_s_setprio(0);
  };

  bf16x8 afA[4], bgA[3];   // ks0 set
  bf16x8 afB[4], bgB[3];   // ks1 set

  // prologue: tile 0 staged and landed
  stage(0, 0);
  asm volatile("s_waitcnt vmcnt(0)" ::: "memory");
  __builtin_amdgcn_s_barrier();

  for (int kt = 0; kt < KTT; ++kt) {
    const ushort_t* base = &lds[kt & 1][0];
    if (kt + 1 < KTT) stage((kt + 1) & 1, kt + 1);   // into the half freed by iter kt-1
    readFrags(base, ksw0, afA, bgA);
    readFrags(base, ksw1, afB, bgB);                 // in flight under burst A
    burst(afA, bgA);

    if (kt + 1 < KTT) {
      // all this buffer's reads complete (WAR fence for next iter's stage into it)
      asm volatile("s_waitcnt lgkmcnt(0)" ::: "memory");
      asm volatile("s_waitcnt vmcnt(0)" ::: "memory");  // tile kt+1 landed
      __builtin_amdgcn_s_barrier();
      __builtin_amdgcn_sched_barrier(0);               // pin burstB AFTER the barrier
    }
    burst(afB, bgB);                                   // staggers MFMA across barrier

    if (kt == 1) {   // k 0..127 (= x tiles) done: capture i_n, restart for h_n
      #pragma unroll
      for (int a = 0; a < 4; ++a) { accin[a] = accN[a]; accN[a] = Z4; }
    }
  }

  // epilogue: gates + recurrence, bf16 state
  // C/D layout: col = lane&15, row = (lane>>4)*4 + q
  const int lqb = lhi * 4;
  const int j = col0 + wn * 16 + lr;
  const float br  = b_ih[j] + b_hh[j];
  const float bz  = b_ih[HID + j] + b_hh[HID + j];
  const float bin = b_ih[2 * HID + j];
  const float bhn = b_hh[2 * HID + j];
  #pragma unroll
  for (int fm = 0; fm < 4; ++fm) {
    #pragma unroll
    for (int q = 0; q < 4; ++q) {
      const int row = row0 + wm * 64 + fm * 16 + lqb + q;
      const size_t off = (size_t)row * HID + j;
      const float hp = bf2f(hbp[off]);
      const float rr = sigmoidf_(accr[fm][q] + br);
      const float zz = sigmoidf_(accz[fm][q] + bz);
      const float nn = tanhf_(accin[fm][q] + bin + rr * (accN[fm][q] + bhn));
      const float hv = (1.0f - zz) * nn + zz * hp;
      hbn[off] = f2bf(hv);
    }
  }
}

// ---------------- decoder fc: out = prev + h_new @ fc_w^T + fc_b; also emit next x ----
// 64 blocks x 512 threads (8 waves, 8-way K-split of K=2048 -> 256 k/wave)
__global__ __launch_bounds__(512) void fc_kernel(
    const ushort_t* __restrict__ hb,    // [1024][2048] bf16 h_new
    const ushort_t* __restrict__ Wfc,   // [80][2048] bf16
    const float*    __restrict__ fc_b,
    const float*    __restrict__ prev,  // row stride OSTR
    float*          __restrict__ outp,  // d_out + t*IN, row stride OSTR
    ushort_t*       __restrict__ xd)    // [1024][128] bf16 next input
{
  __shared__ float red[8][16][80];
  const int tid = threadIdx.x, lane = tid & 63, wid = tid >> 6;   // wid 0..7
  const int r0 = blockIdx.x * 16;
  const int lr = lane & 15, lk = (lane >> 4) * 8;
  const f32x4 Z4 = {0.f, 0.f, 0.f, 0.f};
  f32x4 acc[5];
  #pragma unroll
  for (int f = 0; f < 5; ++f) acc[f] = Z4;
  const int kbase = wid * 256;
  #pragma unroll
  for (int ks = 0; ks < 8; ++ks) {
    const int k = kbase + ks * 32 + lk;
    bf16x8 a = *reinterpret_cast<const bf16x8*>(&hb[(size_t)(r0 + lr) * HID + k]);
    #pragma unroll
    for (int f = 0; f < 5; ++f) {
      bf16x8 b = *reinterpret_cast<const bf16x8*>(&Wfc[(size_t)(f * 16 + lr) * HID + k]);
      acc[f] = mfma16(a, b, acc[f]);
    }
  }
  #pragma unroll
  for (int f = 0; f < 5; ++f)
    #pragma unroll
    for (int q = 0; q < 4; ++q)
      red[wid][(lane >> 4) * 4 + q][f * 16 + lr] = acc[f][q];
  __syncthreads();

  if (tid < 256) {
    const int rowi = tid >> 4;          // 0..15
    const int j0   = (tid & 15) * 8;    // 0..120
    const int b_   = r0 + rowi;
    #pragma unroll
    for (int jj = 0; jj < 8; ++jj) {
      const int j = j0 + jj;
      float ov = 0.f;
      if (j < IN) {
        float s = 0.f;
        #pragma unroll
        for (int w = 0; w < 8; ++w) s += red[w][rowi][j];
        ov = prev[(size_t)b_ * OSTR + j] + fc_b[j] + s;
        outp[(size_t)b_ * OSTR + j] = ov;
      }
      xd[b_ * KX + j] = f2bf(j < IN ? ov : 0.f);
    }
  }
}

// ---------------- host launch ----------------
extern "C" void kernel_launch(void* const* d_in, const int* in_sizes, int n_in,
                              void* d_out, int out_size, void* d_ws, size_t ws_size,
                              hipStream_t stream) {
  const float* enc = (const float*)d_in[0];
  const float* dec = (const float*)d_in[1];
  const float* Wih = (const float*)d_in[2];
  const float* Whh = (const float*)d_in[3];
  const float* bih = (const float*)d_in[4];
  const float* bhh = (const float*)d_in[5];
  const float* fcw = (const float*)d_in[6];
  const float* fcb = (const float*)d_in[7];
  float* out = (float*)d_out;

  char* ws = (char*)d_ws;
  ushort_t* Wp  = (ushort_t*)ws;  ws += (size_t)6144 * KP * 2;          // 26.7 MB
  ushort_t* xe  = (ushort_t*)ws;  ws += (size_t)SENC * BATCH * KX * 2;  // 12.8 MB
  ushort_t* xd  = (ushort_t*)ws;  ws += (size_t)BATCH * KX * 2;         // 256 KB
  ushort_t* Wfc = (ushort_t*)ws;  ws += (size_t)80 * HID * 2;           // 320 KB
  ushort_t* hb0 = (ushort_t*)ws;  ws += (size_t)BATCH * HID * 2;
  ushort_t* hb1 = (ushort_t*)ws;  ws += (size_t)BATCH * HID * 2;
  ushort_t* hbp[2] = {hb0, hb1};

  pack_W  <<<(6144 * KP + 255) / 256, 256, 0, stream>>>(Wih, Whh, Wp);
  pack_xe <<<(SENC * BATCH * KX + 255) / 256, 256, 0, stream>>>(enc, xe);
  pack_xd0<<<(BATCH * KX + 255) / 256, 256, 0, stream>>>(dec, xd);
  pack_fc <<<(80 * HID + 255) / 256, 256, 0, stream>>>(fcw, Wfc);
  hipMemsetAsync(hb0, 0, (size_t)BATCH * HID * 2, stream);

  for (int s = 0; s < SENC + TDEC; ++s) {
    const ushort_t* xsrc = (s < SENC) ? (xe + (size_t)s * BATCH * KX) : xd;
    gru_step_kernel<<<512, 256, 0, stream>>>(xsrc, hbp[s & 1], Wp, bih, bhh,
                                             hbp[(s + 1) & 1]);
    if (s >= SENC) {
      const int t = s - SENC;
      const float* prev = (t == 0) ? dec : (out + (size_t)(t - 1) * IN);
      fc_kernel<<<64, 512, 0, stream>>>(hbp[(s + 1) & 1], Wfc, fcb, prev,
                                        out + (size_t)t * IN, xd);
    }
  }
}

// Round 14
// 2570.000 us; speedup vs baseline: 2.2773x; 1.0351x over previous
//
#include <hip/hip_runtime.h>
#include <cstdint>
#include <cstddef>

#define DI __device__ __forceinline__

typedef __bf16 bf16x8 __attribute__((ext_vector_type(8)));
typedef float  f32x4  __attribute__((ext_vector_type(4)));
typedef unsigned short ushort_t;

constexpr int BATCH = 1024;
constexpr int HID   = 2048;
constexpr int IN    = 76;
constexpr int SENC  = 49;
constexpr int TDEC  = 25;
constexpr int KX    = 128;          // x padded to 128 cols
constexpr int KP    = KX + HID;     // 2176 packed K
constexpr int BK    = 64;           // K-step (one LDS tile)
constexpr int KTT   = KP / BK;      // 34 K-steps
constexpr int OSTR  = TDEC * IN;    // 1900 (row stride of decoder_inputs and d_out)

DI unsigned short f2bf(float f) {
  union { float f; unsigned u; } v; v.f = f;
  unsigned u = v.u;
  return (unsigned short)((u + 0x7fffu + ((u >> 16) & 1u)) >> 16);  // RTNE
}

DI float bf2f(unsigned short h) {
  union { unsigned u; float f; } v; v.u = ((unsigned)h) << 16;
  return v.f;
}

DI f32x4 mfma16(bf16x8 a, bf16x8 b, f32x4 c) {
  return __builtin_amdgcn_mfma_f32_16x16x32_bf16(a, b, c, 0, 0, 0);
}

DI void gload_lds16(const void* g, void* l) {
  __builtin_amdgcn_global_load_lds((const __attribute__((address_space(1))) void*)g,
                                   (__attribute__((address_space(3))) void*)l,
                                   16, 0, 0);
}

DI float sigmoidf_(float x) { return 1.0f / (1.0f + __expf(-x)); }
DI float tanhf_(float x)    { return 1.0f - 2.0f / (1.0f + __expf(2.0f * x)); }

// ---------------- packing kernels (run once per launch) ----------------

__global__ void pack_W(const float* __restrict__ Wih, const float* __restrict__ Whh,
                       ushort_t* __restrict__ Wp) {
  int idx = blockIdx.x * 256 + threadIdx.x;
  if (idx >= 6144 * KP) return;
  int n = idx / KP;
  int k = idx - n * KP;
  float v = 0.f;
  if (k < IN)        v = Wih[(size_t)n * IN + k];
  else if (k >= KX)  v = Whh[(size_t)n * HID + (k - KX)];
  Wp[idx] = f2bf(v);
}

__global__ void pack_xe(const float* __restrict__ enc, ushort_t* __restrict__ xe) {
  int idx = blockIdx.x * 256 + threadIdx.x;
  if (idx >= SENC * BATCH * KX) return;
  int t = idx >> 17;
  int rem = idx & 131071;
  int b = rem >> 7, k = rem & 127;
  float v = (k < IN) ? enc[(size_t)b * (SENC * IN) + t * IN + k] : 0.f;
  xe[idx] = f2bf(v);
}

__global__ void pack_xd0(const float* __restrict__ dec, ushort_t* __restrict__ xd) {
  int idx = blockIdx.x * 256 + threadIdx.x;
  if (idx >= BATCH * KX) return;
  int b = idx >> 7, k = idx & 127;
  float v = (k < IN) ? dec[(size_t)b * OSTR + k] : 0.f;
  xd[idx] = f2bf(v);
}

__global__ void pack_fc(const float* __restrict__ fcw, ushort_t* __restrict__ Wfc) {
  int idx = blockIdx.x * 256 + threadIdx.x;
  if (idx >= 80 * HID) return;
  int n = idx >> 11, k = idx & 2047;
  float v = (n < IN) ? fcw[(size_t)n * HID + k] : 0.f;
  Wfc[idx] = f2bf(v);
}

// ---------------- fused GRU step: 2 blocks/CU for cross-block stall filling ----------
// grid 512 (8 m x 64 n), block 256 (4 waves, 2m x 2n; wave 64 rows x 48 gate-cols).
// Per-block tile 128 rows x 32 n-cols; B = 96 Wp rows. LDS 2 x 28 KB = 56 KB/block ->
// TWO independent blocks per CU: when one block sits in its vmcnt+barrier drain, the
// other block's waves feed the MFMA pipe (m114 cross-wave overlap, phase-decoupled).
// Best-measured configuration (R9: 2583 us total, ~30 us/step, 913 TF-equivalent —
// the documented m97-class plain-HIP structural ceiling for this geometry).
__global__ __launch_bounds__(256, 2) void gru_step_kernel(
    const ushort_t* __restrict__ x,    // [1024][128] bf16
    const ushort_t* __restrict__ hbp,  // [1024][2048] bf16 h_prev
    const ushort_t* __restrict__ Wp,   // [6144][2176] bf16
    const float*    __restrict__ b_ih,
    const float*    __restrict__ b_hh,
    ushort_t*       __restrict__ hbn)  // [1024][2048] bf16 h_new
{
  __shared__ ushort_t lds[2][(128 + 96) * BK];   // A 128x64 + B 96x64 = 28 KB x 2

  const int tid  = threadIdx.x;
  const int lane = tid & 63;
  const int wid  = tid >> 6;        // 0..3
  const int bid  = blockIdx.x;
  // XCD mapping: bid%8 -> XCD (round-robin dispatch); same-XCD blocks share 8 W panels
  // (8 n_grps x 96 rows x 4.25 KB = 3.3 MB < 4 MB per-XCD L2)
  const int xcd   = bid & 7;
  const int idx   = bid >> 3;                     // 0..63
  const int m_grp = idx & 7;                      // 0..7
  const int n_grp = xcd + 8 * (idx >> 3);         // 0..63
  const int row0  = m_grp * 128;
  const int col0  = n_grp * 32;
  const int wm = wid >> 1;          // 0..1 : 64-row half
  const int wn = wid & 1;           // 0..1 : 16-col half (per gate)

  const f32x4 Z4 = {0.f, 0.f, 0.f, 0.f};
  f32x4 accr[4], accz[4], accN[4], accin[4];
  #pragma unroll
  for (int a = 0; a < 4; ++a) { accr[a] = Z4; accz[a] = Z4; accN[a] = Z4; accin[a] = Z4; }

  // staging constants (proven): chunk = 8 rows x 64 cols (1 KB); row = lane>>3;
  // source 16B-group pre-XORed with (row&7) so linear LDS dest holds swizzled layout
  const int srow  = lane >> 3;
  const int swcol = (((lane & 7) ^ (srow & 7)) << 3);   // elements

  // fragment-read constants (consumer-side XOR, proven)
  const int lr  = lane & 15;
  const int lhi = lane >> 4;
  const int bc  = lhi * 16;                               // byte col, pre-swizzle
  const int ksw0 = ((bc)      ^ ((lane & 7) << 4)) >> 1;  // element offsets
  const int ksw1 = ((64 + bc) ^ ((lane & 7) << 4)) >> 1;

  auto stage = [&](int buf, int kt) {
    const ushort_t* asrc; int astr, ak0;
    if (kt < 2) { asrc = x;   astr = KX;  ak0 = kt * BK; }
    else        { asrc = hbp; astr = HID; ak0 = (kt - 2) * BK; }
    ushort_t* Lb = &lds[buf][0];
    #pragma unroll
    for (int c = 0; c < 4; ++c) {                 // A: 4 chunks/wave (16 total = 128 rows)
      const int chunk = wid * 4 + c;              // 0..15
      const ushort_t* g = asrc + (size_t)(row0 + chunk * 8 + srow) * astr + ak0 + swcol;
      gload_lds16(g, Lb + chunk * 512);
    }
    const int wk0 = kt * BK;
    #pragma unroll
    for (int c = 0; c < 3; ++c) {                 // B: 3 chunks/wave (12 total = 96 rows)
      const int chunk = wid * 3 + c;              // 0..11
      const int brow = chunk * 8 + srow;          // 0..95 (gate*32 + col)
      const int gg = brow >> 5, wi = brow & 31;
      const ushort_t* g = Wp + (size_t)(gg * HID + col0 + wi) * KP + wk0 + swcol;
      gload_lds16(g, Lb + 128 * BK + chunk * 512);
    }
  };

  auto readFrags = [&](const ushort_t* base, int ko, bf16x8 af[4], bf16x8 bg[3]) {
    #pragma unroll
    for (int fm = 0; fm < 4; ++fm)
      af[fm] = *reinterpret_cast<const bf16x8*>(&base[(wm * 64 + fm * 16 + lr) * BK + ko]);
    #pragma unroll
    for (int g = 0; g < 3; ++g)
      bg[g] = *reinterpret_cast<const bf16x8*>(
          &base[128 * BK + (g * 32 + wn * 16 + lr) * BK + ko]);
  };

  auto burst = [&](bf16x8 af[4], bf16x8 bg[3]) {
    __builtin_amdgcn_s_setprio(1);
    #pragma unroll
    for (int fm = 0; fm < 4; ++fm) {
      accr[fm] = mfma16(af[fm], bg[0], accr[fm]);
      accz[fm] = mfma16(af[fm], bg[1], accz[fm]);
      accN[fm] = mfma16(af[fm], bg[2], accN[fm]);
    }
    __builtin_amdgcn_s_setprio(0);
  };

  bf16x8 afA[4], bgA[3];   // ks0 set
  bf16x8 afB[4], bgB[3];   // ks1 set

  // prologue: tile 0 staged and landed
  stage(0, 0);
  asm volatile("s_waitcnt vmcnt(0)" ::: "memory");
  __builtin_amdgcn_s_barrier();

  for (int kt = 0; kt < KTT; ++kt) {
    const ushort_t* base = &lds[kt & 1][0];
    if (kt + 1 < KTT) stage((kt + 1) & 1, kt + 1);   // into the half freed by iter kt-1
    readFrags(base, ksw0, afA, bgA);
    readFrags(base, ksw1, afB, bgB);                 // in flight under burst A
    burst(afA, bgA);
    burst(afB, bgB);

    if (kt == 1) {   // k 0..127 (= x tiles) done: capture i_n, restart for h_n
      #pragma unroll
      for (int a = 0; a < 4; ++a) { accin[a] = accN[a]; accN[a] = Z4; }
    }

    if (kt + 1 < KTT) {
      asm volatile("s_waitcnt vmcnt(0)" ::: "memory");  // tile kt+1 landed
      __builtin_amdgcn_s_barrier();
    }
  }

  // epilogue: gates + recurrence, bf16 state
  // C/D layout: col = lane&15, row = (lane>>4)*4 + q
  const int lqb = lhi * 4;
  const int j = col0 + wn * 16 + lr;
  const float br  = b_ih[j] + b_hh[j];
  const float bz  = b_ih[HID + j] + b_hh[HID + j];
  const float bin = b_ih[2 * HID + j];
  const float bhn = b_hh[2 * HID + j];
  #pragma unroll
  for (int fm = 0; fm < 4; ++fm) {
    #pragma unroll
    for (int q = 0; q < 4; ++q) {
      const int row = row0 + wm * 64 + fm * 16 + lqb + q;
      const size_t off = (size_t)row * HID + j;
      const float hp = bf2f(hbp[off]);
      const float rr = sigmoidf_(accr[fm][q] + br);
      const float zz = sigmoidf_(accz[fm][q] + bz);
      const float nn = tanhf_(accin[fm][q] + bin + rr * (accN[fm][q] + bhn));
      const float hv = (1.0f - zz) * nn + zz * hp;
      hbn[off] = f2bf(hv);
    }
  }
}

// ---------------- decoder fc: out = prev + h_new @ fc_w^T + fc_b; also emit next x (bf16) ----
__global__ __launch_bounds__(256) void fc_kernel(
    const ushort_t* __restrict__ hb,    // [1024][2048] bf16 h_new
    const ushort_t* __restrict__ Wfc,   // [80][2048] bf16
    const float*    __restrict__ fc_b,
    const float*    __restrict__ prev,  // row stride OSTR
    float*          __restrict__ outp,  // d_out + t*IN, row stride OSTR
    ushort_t*       __restrict__ xd)    // [1024][128] bf16 next input
{
  __shared__ float red[4][16][80];
  const int tid = threadIdx.x, lane = tid & 63, wid = tid >> 6;
  const int r0 = blockIdx.x * 16;
  const int lr = lane & 15, lk = (lane >> 4) * 8;
  const f32x4 Z4 = {0.f, 0.f, 0.f, 0.f};
  f32x4 acc[5];
  #pragma unroll
  for (int f = 0; f < 5; ++f) acc[f] = Z4;
  const int kbase = wid * 512;
  #pragma unroll
  for (int ks = 0; ks < 16; ++ks) {
    const int k = kbase + ks * 32 + lk;
    bf16x8 a = *reinterpret_cast<const bf16x8*>(&hb[(size_t)(r0 + lr) * HID + k]);
    #pragma unroll
    for (int f = 0; f < 5; ++f) {
      bf16x8 b = *reinterpret_cast<const bf16x8*>(&Wfc[(size_t)(f * 16 + lr) * HID + k]);
      acc[f] = mfma16(a, b, acc[f]);
    }
  }
  #pragma unroll
  for (int f = 0; f < 5; ++f)
    #pragma unroll
    for (int q = 0; q < 4; ++q)
      red[wid][(lane >> 4) * 4 + q][f * 16 + lr] = acc[f][q];
  __syncthreads();

  const int rowi = tid >> 4;          // 0..15
  const int j0   = (tid & 15) * 8;    // 0..120
  const int b_   = r0 + rowi;
  #pragma unroll
  for (int jj = 0; jj < 8; ++jj) {
    const int j = j0 + jj;
    float ov = 0.f;
    if (j < IN) {
      float s = red[0][rowi][j] + red[1][rowi][j] + red[2][rowi][j] + red[3][rowi][j];
      ov = prev[(size_t)b_ * OSTR + j] + fc_b[j] + s;
      outp[(size_t)b_ * OSTR + j] = ov;
    }
    xd[b_ * KX + j] = f2bf(j < IN ? ov : 0.f);
  }
}

// ---------------- host launch ----------------
extern "C" void kernel_launch(void* const* d_in, const int* in_sizes, int n_in,
                              void* d_out, int out_size, void* d_ws, size_t ws_size,
                              hipStream_t stream) {
  const float* enc = (const float*)d_in[0];
  const float* dec = (const float*)d_in[1];
  const float* Wih = (const float*)d_in[2];
  const float* Whh = (const float*)d_in[3];
  const float* bih = (const float*)d_in[4];
  const float* bhh = (const float*)d_in[5];
  const float* fcw = (const float*)d_in[6];
  const float* fcb = (const float*)d_in[7];
  float* out = (float*)d_out;

  char* ws = (char*)d_ws;
  ushort_t* Wp  = (ushort_t*)ws;  ws += (size_t)6144 * KP * 2;          // 26.7 MB
  ushort_t* xe  = (ushort_t*)ws;  ws += (size_t)SENC * BATCH * KX * 2;  // 12.8 MB
  ushort_t* xd  = (ushort_t*)ws;  ws += (size_t)BATCH * KX * 2;         // 256 KB
  ushort_t* Wfc = (ushort_t*)ws;  ws += (size_t)80 * HID * 2;           // 320 KB
  ushort_t* hb0 = (ushort_t*)ws;  ws += (size_t)BATCH * HID * 2;
  ushort_t* hb1 = (ushort_t*)ws;  ws += (size_t)BATCH * HID * 2;
  ushort_t* hbp[2] = {hb0, hb1};

  pack_W  <<<(6144 * KP + 255) / 256, 256, 0, stream>>>(Wih, Whh, Wp);
  pack_xe <<<(SENC * BATCH * KX + 255) / 256, 256, 0, stream>>>(enc, xe);
  pack_xd0<<<(BATCH * KX + 255) / 256, 256, 0, stream>>>(dec, xd);
  pack_fc <<<(80 * HID + 255) / 256, 256, 0, stream>>>(fcw, Wfc);
  hipMemsetAsync(hb0, 0, (size_t)BATCH * HID * 2, stream);

  for (int s = 0; s < SENC + TDEC; ++s) {
    const ushort_t* xsrc = (s < SENC) ? (xe + (size_t)s * BATCH * KX) : xd;
    gru_step_kernel<<<512, 256, 0, stream>>>(xsrc, hbp[s & 1], Wp, bih, bhh,
                                             hbp[(s + 1) & 1]);
    if (s >= SENC) {
      const int t = s - SENC;
      const float* prev = (t == 0) ? dec : (out + (size_t)(t - 1) * IN);
      fc_kernel<<<64, 256, 0, stream>>>(hbp[(s + 1) & 1], Wfc, fcb, prev,
                                        out + (size_t)t * IN, xd);
    }
  }
}